// Round 3
// baseline (158.317 us; speedup 1.0000x reference)
//
#include <hip/hip_runtime.h>

// KnowledgeGraphEmbedding: out[4][P]
//   dist[p] = || Lp_w[p] @ wi - Rp_w[p] @ wj ||^2
//   out = { dist*is_edge, dist*is_not, is_edge, is_not }
//
// Memory-bound: 2 * P*H*E*4B = 737 MB streamed once.
// R2: split into (projection -> ws) + (reduce) to get 32 waves/CU and one
//     contiguous stream per block. Fallback to fused kernel if ws too small.

#define KGE_P 1024
#define KGE_H 300
#define KGE_E 300
#define KGE_E4 75    // float4 chunks per row
#define KGE_TAILC 11 // KGE_E4 - 64 chunks handled by lanes 0..10
#define KGE_HALF 150

__device__ __forceinline__ float dot4(float4 x, float4 y) {
    return x.x * y.x + x.y * y.y + x.z * y.z + x.w * y.w;
}

// ---------------- Kernel 1: per-row projections -> ws[p][m][h] --------------
// grid = 4*P blocks: b -> p = b>>2, m = b&1 (0:L/wi, 1:R/wj), half = (b>>1)&1
__global__ __launch_bounds__(256) void kge_proj(
    const float* __restrict__ tag_rep,
    const float* __restrict__ Lp_w,
    const float* __restrict__ Rp_w,
    const int*   __restrict__ tag1_idx,
    const int*   __restrict__ tag2_idx,
    float*       __restrict__ ws)
{
    __shared__ float s_w[KGE_E];

    const int b    = blockIdx.x;
    const int p    = b >> 2;
    const int m    = b & 1;
    const int half = (b >> 1) & 1;
    const int tid  = threadIdx.x;
    const int lane = tid & 63;
    const int wave = tid >> 6;

    const int tag = (m == 0) ? tag1_idx[0] : tag2_idx[0];
    const float* wrow = tag_rep + (size_t)tag * KGE_E;
    for (int i = tid; i < KGE_E; i += 256) s_w[i] = wrow[i];
    __syncthreads();

    const float4* w4 = (const float4*)s_w;
    const float4 a0 = w4[lane];
    float4 a1 = make_float4(0.f, 0.f, 0.f, 0.f);
    if (lane < KGE_TAILC) a1 = w4[64 + lane];

    const float* mat = ((m == 0) ? Lp_w : Rp_w) + (size_t)p * KGE_H * KGE_E;
    float* wsrow = ws + (size_t)(p * 2 + m) * KGE_H;

    const int h0 = half * KGE_HALF;
    const int h1 = h0 + KGE_HALF;
    for (int h = h0 + wave; h < h1; h += 4) {
        const float4* __restrict__ row = (const float4*)(mat + (size_t)h * KGE_E);
        float4 v0 = row[lane];
        float s = dot4(v0, a0);
        if (lane < KGE_TAILC) {
            float4 v1 = row[64 + lane];
            s += dot4(v1, a1);
        }
        #pragma unroll
        for (int off = 32; off >= 1; off >>= 1)
            s += __shfl_xor(s, off, 64);
        if (lane == 0) wsrow[h] = s;
    }
}

// ---------------- Kernel 2: dist + outputs ----------------------------------
// grid = P blocks of 1 wave
__global__ __launch_bounds__(64) void kge_dist(
    const float* __restrict__ ws,
    const int*   __restrict__ relation,
    float*       __restrict__ out)
{
    const int p    = blockIdx.x;
    const int lane = threadIdx.x;

    const float* li = ws + (size_t)(p * 2 + 0) * KGE_H;
    const float* rj = ws + (size_t)(p * 2 + 1) * KGE_H;

    float acc = 0.0f;
    for (int h = lane; h < KGE_H; h += 64) {
        float d = li[h] - rj[h];
        acc += d * d;
    }
    #pragma unroll
    for (int off = 32; off >= 1; off >>= 1)
        acc += __shfl_xor(acc, off, 64);

    if (lane == 0) {
        const int rel = relation[p];
        const float is_edge = (rel == 1) ? 1.0f : 0.0f;
        const float is_not  = (rel == 0) ? 1.0f : 0.0f;
        out[0 * KGE_P + p] = acc * is_edge;
        out[1 * KGE_P + p] = acc * is_not;
        out[2 * KGE_P + p] = is_edge;
        out[3 * KGE_P + p] = is_not;
    }
}

// ---------------- Fallback: fused single kernel (proven R0) -----------------
__global__ __launch_bounds__(256) void kge_fused(
    const float* __restrict__ tag_rep,
    const float* __restrict__ Lp_w,
    const float* __restrict__ Rp_w,
    const int*   __restrict__ relation,
    const int*   __restrict__ tag1_idx,
    const int*   __restrict__ tag2_idx,
    float*       __restrict__ out)
{
    __shared__ float s_wi[KGE_E];
    __shared__ float s_wj[KGE_E];
    __shared__ float s_wave[4];

    const int p    = blockIdx.x;
    const int tid  = threadIdx.x;
    const int lane = tid & 63;
    const int wave = tid >> 6;

    {
        const int t1 = tag1_idx[0];
        const int t2 = tag2_idx[0];
        const float* wi = tag_rep + (size_t)t1 * KGE_E;
        const float* wj = tag_rep + (size_t)t2 * KGE_E;
        for (int i = tid; i < KGE_E; i += 256) {
            s_wi[i] = wi[i];
            s_wj[i] = wj[i];
        }
    }
    __syncthreads();

    const float4* s_wi4 = (const float4*)s_wi;
    const float4* s_wj4 = (const float4*)s_wj;
    const float4 a0 = s_wi4[lane];
    const float4 b0 = s_wj4[lane];
    float4 a1 = make_float4(0.f, 0.f, 0.f, 0.f);
    float4 b1 = a1;
    if (lane < KGE_TAILC) {
        a1 = s_wi4[64 + lane];
        b1 = s_wj4[64 + lane];
    }

    const float4* __restrict__ Lbase = (const float4*)(Lp_w + (size_t)p * KGE_H * KGE_E);
    const float4* __restrict__ Rbase = (const float4*)(Rp_w + (size_t)p * KGE_H * KGE_E);

    float dist_acc = 0.0f;
    for (int h = wave; h < KGE_H; h += 4) {
        const float4* __restrict__ Lr = Lbase + (size_t)h * KGE_E4;
        const float4* __restrict__ Rr = Rbase + (size_t)h * KGE_E4;
        float4 lv = Lr[lane];
        float4 rv = Rr[lane];
        float s = dot4(lv, a0) - dot4(rv, b0);
        if (lane < KGE_TAILC) {
            float4 lb = Lr[64 + lane];
            float4 rb = Rr[64 + lane];
            s += dot4(lb, a1) - dot4(rb, b1);
        }
        #pragma unroll
        for (int off = 32; off >= 1; off >>= 1)
            s += __shfl_xor(s, off, 64);
        dist_acc += s * s;
    }

    if (lane == 0) s_wave[wave] = dist_acc;
    __syncthreads();

    if (tid == 0) {
        const float dist = s_wave[0] + s_wave[1] + s_wave[2] + s_wave[3];
        const int rel = relation[p];
        const float is_edge = (rel == 1) ? 1.0f : 0.0f;
        const float is_not  = (rel == 0) ? 1.0f : 0.0f;
        out[0 * KGE_P + p] = dist * is_edge;
        out[1 * KGE_P + p] = dist * is_not;
        out[2 * KGE_P + p] = is_edge;
        out[3 * KGE_P + p] = is_not;
    }
}

extern "C" void kernel_launch(void* const* d_in, const int* in_sizes, int n_in,
                              void* d_out, int out_size, void* d_ws, size_t ws_size,
                              hipStream_t stream) {
    const float* tag_rep  = (const float*)d_in[0];
    const float* Lp_w     = (const float*)d_in[1];
    const float* Rp_w     = (const float*)d_in[2];
    const int*   relation = (const int*)d_in[3];
    const int*   tag1_idx = (const int*)d_in[4];
    const int*   tag2_idx = (const int*)d_in[5];
    float*       out      = (float*)d_out;

    const size_t ws_needed = (size_t)2 * KGE_P * KGE_H * sizeof(float); // 2.46 MB
    if (ws_size >= ws_needed) {
        float* ws = (float*)d_ws;
        kge_proj<<<4 * KGE_P, 256, 0, stream>>>(tag_rep, Lp_w, Rp_w,
                                                tag1_idx, tag2_idx, ws);
        kge_dist<<<KGE_P, 64, 0, stream>>>(ws, relation, out);
    } else {
        kge_fused<<<KGE_P, 256, 0, stream>>>(tag_rep, Lp_w, Rp_w,
                                             relation, tag1_idx, tag2_idx, out);
    }
}

// Round 4
// 135.694 us; speedup vs baseline: 1.1667x; 1.1667x over previous
//
#include <hip/hip_runtime.h>

// KnowledgeGraphEmbedding: out[4][P]
//   dist[p] = || Lp_w[p] @ wi - Rp_w[p] @ wj ||^2
//   out = { dist*is_edge, dist*is_not, is_edge, is_not }
//
// Memory-bound: 2 * P*H*E*4B = 737 MB streamed once (read-once, no reuse).
// R3: R0 structure (fastest so far, 139.8 us = 5.28 TB/s) + NON-TEMPORAL
//     loads on the two big streams to bypass L2/L3 fill-evict overhead.

#define KGE_P 1024
#define KGE_H 300
#define KGE_E 300
#define KGE_E4 75    // float4 chunks per row
#define KGE_TAILC 11 // KGE_E4 - 64 chunks handled by lanes 0..10

typedef float f32x4 __attribute__((ext_vector_type(4)));

__device__ __forceinline__ float dot4(f32x4 x, f32x4 y) {
    return x.x * y.x + x.y * y.y + x.z * y.z + x.w * y.w;
}

__global__ __launch_bounds__(256) void kge_fused_nt(
    const float* __restrict__ tag_rep,
    const float* __restrict__ Lp_w,
    const float* __restrict__ Rp_w,
    const int*   __restrict__ relation,
    const int*   __restrict__ tag1_idx,
    const int*   __restrict__ tag2_idx,
    float*       __restrict__ out)
{
    __shared__ float s_wi[KGE_E];
    __shared__ float s_wj[KGE_E];
    __shared__ float s_wave[4];

    const int p    = blockIdx.x;
    const int tid  = threadIdx.x;
    const int lane = tid & 63;
    const int wave = tid >> 6;

    // Stage the two tag-embedding rows into LDS (cached path is fine here).
    {
        const int t1 = tag1_idx[0];
        const int t2 = tag2_idx[0];
        const float* wi = tag_rep + (size_t)t1 * KGE_E;
        const float* wj = tag_rep + (size_t)t2 * KGE_E;
        for (int i = tid; i < KGE_E; i += 256) {
            s_wi[i] = wi[i];
            s_wj[i] = wj[i];
        }
    }
    __syncthreads();

    const f32x4* s_wi4 = (const f32x4*)s_wi;
    const f32x4* s_wj4 = (const f32x4*)s_wj;
    const f32x4 a0 = s_wi4[lane];
    const f32x4 b0 = s_wj4[lane];
    f32x4 a1 = (f32x4)(0.0f);
    f32x4 b1 = (f32x4)(0.0f);
    if (lane < KGE_TAILC) {
        a1 = s_wi4[64 + lane];
        b1 = s_wj4[64 + lane];
    }

    const f32x4* __restrict__ Lbase = (const f32x4*)(Lp_w + (size_t)p * KGE_H * KGE_E);
    const f32x4* __restrict__ Rbase = (const f32x4*)(Rp_w + (size_t)p * KGE_H * KGE_E);

    float dist_acc = 0.0f;

    // Each wave owns rows h = wave, wave+4, ... (75 rows).
    for (int h = wave; h < KGE_H; h += 4) {
        const f32x4* __restrict__ Lr = Lbase + (size_t)h * KGE_E4;
        const f32x4* __restrict__ Rr = Rbase + (size_t)h * KGE_E4;

        f32x4 lv = __builtin_nontemporal_load(Lr + lane);
        f32x4 rv = __builtin_nontemporal_load(Rr + lane);
        float s = dot4(lv, a0) - dot4(rv, b0);
        if (lane < KGE_TAILC) {
            f32x4 lb = __builtin_nontemporal_load(Lr + 64 + lane);
            f32x4 rb = __builtin_nontemporal_load(Rr + 64 + lane);
            s += dot4(lb, a1) - dot4(rb, b1);
        }
        #pragma unroll
        for (int off = 32; off >= 1; off >>= 1)
            s += __shfl_xor(s, off, 64);
        dist_acc += s * s;
    }

    if (lane == 0) s_wave[wave] = dist_acc;
    __syncthreads();

    if (tid == 0) {
        const float dist = s_wave[0] + s_wave[1] + s_wave[2] + s_wave[3];
        const int rel = relation[p];
        const float is_edge = (rel == 1) ? 1.0f : 0.0f;
        const float is_not  = (rel == 0) ? 1.0f : 0.0f;
        out[0 * KGE_P + p] = dist * is_edge;
        out[1 * KGE_P + p] = dist * is_not;
        out[2 * KGE_P + p] = is_edge;
        out[3 * KGE_P + p] = is_not;
    }
}

extern "C" void kernel_launch(void* const* d_in, const int* in_sizes, int n_in,
                              void* d_out, int out_size, void* d_ws, size_t ws_size,
                              hipStream_t stream) {
    const float* tag_rep  = (const float*)d_in[0];
    const float* Lp_w     = (const float*)d_in[1];
    const float* Rp_w     = (const float*)d_in[2];
    const int*   relation = (const int*)d_in[3];
    const int*   tag1_idx = (const int*)d_in[4];
    const int*   tag2_idx = (const int*)d_in[5];
    float*       out      = (float*)d_out;

    kge_fused_nt<<<KGE_P, 256, 0, stream>>>(tag_rep, Lp_w, Rp_w,
                                            relation, tag1_idx, tag2_idx, out);
}